// Round 1
// 3343.288 us; speedup vs baseline: 1.5169x; 1.5169x over previous
//
#include <hip/hip_runtime.h>

typedef long long ll;
typedef __bf16 bf16x8 __attribute__((ext_vector_type(8)));
typedef float f32x4 __attribute__((ext_vector_type(4)));

#define T 2048
#define Dm 1024
#define DFF 4096
#define SPK 512
#define MOE_CH 512   // DFF chunk for MoE staging (8 chunks)

// ---------------- workspace offsets (in floats) ----------------
// Live ranges: xn,q,k,v,av die before MoE; hmid/y alias them.
static const ll OFF_XN    = 0;          // 2048*1024
static const ll OFF_Q     = 2097152;    // 2048*1024
static const ll OFF_K     = 4194304;    // 2048*1024
static const ll OFF_V     = 6291456;    // 2048*1024
static const ll OFF_AV    = 8388608;    // 2048*1024
static const ll OFF_X1    = 10485760;   // 2048*1024  (live to the end)
static const ll OFF_X2N   = 12582912;   // 2048*1024  (live through MoE GEMM1)
static const ll OFF_QI    = 14680064;   // 2048*256
static const ll OFF_KI    = 15204352;   // 2048*64
static const ll OFF_HW    = 15335424;   // 2048*4
static const ll OFF_PROBS = 15343616;   // 2048*8
static const ll OFF_GATES = 15360000;   // 2048*2
static const ll OFF_TOPI  = 15364096;   // 2048*2 int
static const ll OFF_PTOK  = 15368192;   // 5120 int
static const ll OFF_PGATE = 15373312;   // 5120
static const ll OFF_TOKP  = 15378432;   // 2048*2 int
static const ll OFF_CNT   = 15382528;   // 8 int   -- memset-0 region starts here
static const ll OFF_PSUM  = 15382536;   // 8 float
static const ll OFF_OFFS  = 15382544;   // 9 int
static const ll OFF_CURS  = 15382560;   // 8 int   -- memset-0 region = 64 floats
static const ll OFF_SELI  = 15382592;   // 2048*512 int
static const ll OFF_SELC  = 16431168;   // 2048 int
// total ws = 16433216 floats = ~62.7 MiB
static const ll OFF_HMID  = OFF_Q;      // 5120*512  -> ends 4718592
static const ll OFF_Y     = 4718592;    // 5120*1024 -> ends 9961472 (< OFF_X1)

// ---------------- RMSNorm ----------------
__global__ __launch_bounds__(256) void rmsnorm_k(const float* __restrict__ x,
                                                 const float* __restrict__ w,
                                                 float* __restrict__ o) {
    int t = blockIdx.x, tid = threadIdx.x;
    __shared__ float red[4];
    float4 xv = ((const float4*)(x + (ll)t * Dm))[tid];
    float ss = xv.x * xv.x + xv.y * xv.y + xv.z * xv.z + xv.w * xv.w;
#pragma unroll
    for (int off = 32; off >= 1; off >>= 1) ss += __shfl_xor(ss, off);
    int lane = tid & 63, wv = tid >> 6;
    if (lane == 0) red[wv] = ss;
    __syncthreads();
    float tot = red[0] + red[1] + red[2] + red[3];
    float sc = 1.0f / sqrtf(tot * (1.0f / 1024.0f) + 1e-6f);
    float4 wv4 = ((const float4*)w)[tid];
    float4 ov;
    ov.x = xv.x * sc * wv4.x; ov.y = xv.y * sc * wv4.y;
    ov.z = xv.z * sc * wv4.z; ov.w = xv.w * sc * wv4.w;
    ((float4*)(o + (ll)t * Dm))[tid] = ov;
}

// ---------------- generic tiled fp32 GEMM (kept for indexer path: bit-stable) ----------------
// C[m][n] = A[m][:] @ B[:][n], tile 128x64, BK=8, 256 thr, 8x4 per thread.
// flags: 1=+bias  2=gelu(tanh)  4=+resid[m][n] (ld=ldc)  8=accumulate into C
__global__ __launch_bounds__(256) void gemm_k(
    const float* __restrict__ A, int lda,
    const float* __restrict__ B, int ldb, ll ebB,
    float* __restrict__ C, int ldc,
    const float* __restrict__ bias, int ebBias,
    const float* __restrict__ resid,
    const int* __restrict__ gather,
    const int* __restrict__ gcnt, const int* __restrict__ goff,
    int N, int K, int flags) {
    int e = blockIdx.z;
    int m0, mvalid;
    if (gcnt) {
        int cnt = gcnt[e];
        mvalid = cnt - blockIdx.y * 128;
        if (mvalid <= 0) return;
        if (mvalid > 128) mvalid = 128;
        m0 = goff[e] + blockIdx.y * 128;
    } else {
        m0 = blockIdx.y * 128; mvalid = 128;
    }
    int n0 = blockIdx.x * 64;
    const float* Bp = B + (ll)e * ebB;
    __shared__ float As[8][132];   // +4 pad: 16B-aligned rows, conflict-free
    __shared__ float Bs[8][64];
    int tid = threadIdx.x;
    int tx = tid & 15, ty = tid >> 4;
    int arow = tid >> 1, ak = (tid & 1) * 4;
    int brow = tid >> 4, bn = (tid & 15) * 4;   // only tid<128 loads B
    ll aRow;
    int asrc = (arow < mvalid) ? arow : 0;
    if (gather) aRow = gather[m0 + asrc]; else aRow = m0 + asrc;
    const float* Aptr = A + aRow * (ll)lda + ak;
    bool bin = (tid < 128) && ((n0 + bn) < N);
    const float* Bptr0 = Bp + n0 + bn;
    float acc[8][4];
#pragma unroll
    for (int r = 0; r < 8; r++)
#pragma unroll
        for (int c = 0; c < 4; c++) acc[r][c] = 0.0f;

    for (int k0 = 0; k0 < K; k0 += 8) {
        float4 a4 = *(const float4*)(Aptr + k0);
        float4 b4 = make_float4(0.f, 0.f, 0.f, 0.f);
        if (bin) b4 = *(const float4*)(Bptr0 + (ll)(k0 + brow) * ldb);
        As[ak + 0][arow] = a4.x; As[ak + 1][arow] = a4.y;
        As[ak + 2][arow] = a4.z; As[ak + 3][arow] = a4.w;
        if (tid < 128) *(float4*)&Bs[brow][bn] = b4;
        __syncthreads();
#pragma unroll
        for (int kk = 0; kk < 8; kk++) {
            float4 a0 = *(const float4*)&As[kk][ty * 8];
            float4 a1 = *(const float4*)&As[kk][ty * 8 + 4];
            float4 b0 = *(const float4*)&Bs[kk][tx * 4];
            float aa[8] = {a0.x, a0.y, a0.z, a0.w, a1.x, a1.y, a1.z, a1.w};
            float bb[4] = {b0.x, b0.y, b0.z, b0.w};
#pragma unroll
            for (int r = 0; r < 8; r++)
#pragma unroll
                for (int c = 0; c < 4; c++)
                    acc[r][c] = fmaf(aa[r], bb[c], acc[r][c]);
        }
        __syncthreads();
    }
#pragma unroll
    for (int r = 0; r < 8; r++) {
        int i = ty * 8 + r;
        if (i >= mvalid) continue;
        ll gm = (ll)(m0 + i);
#pragma unroll
        for (int c = 0; c < 4; c++) {
            int j = n0 + tx * 4 + c;
            if (j >= N) continue;
            float vv = acc[r][c];
            if (flags & 1) vv += bias[(ll)e * ebBias + j];
            if (flags & 2) {
                float g = vv;
                vv = 0.5f * g * (1.0f + tanhf(0.7978845608028654f * (g + 0.044715f * g * g * g)));
            }
            if (flags & 4) vv += resid[gm * ldc + j];
            if (flags & 8) vv += C[gm * ldc + j];
            C[gm * ldc + j] = vv;
        }
    }
}

// ---------------- fp32-accurate MFMA GEMM via 3-way bf16 truncation split ----------------
// a = ah + am + al (each bf16-truncated); a*b approximated with 6 MFMA products
// (hh, hm, mh, hl, mm, lh) -> relative error ~2^-22 (fp32-grade, keeps router/top-k
// selections baseline-stable). Tile 128x128, BK=32, 256 thr (4 waves of 64x64).
// Requires: N % 128 == 0, K % 32 == 0, (non-grouped) M % 128 == 0.
// flags identical to gemm_k.
__device__ __forceinline__ void split2(float x0, float x1,
                                       unsigned& h, unsigned& m, unsigned& l) {
    unsigned u0 = __float_as_uint(x0), u1 = __float_as_uint(x1);
    unsigned h0 = u0 & 0xFFFF0000u, h1 = u1 & 0xFFFF0000u;
    float r0 = x0 - __uint_as_float(h0);
    float r1 = x1 - __uint_as_float(h1);
    unsigned v0 = __float_as_uint(r0), v1 = __float_as_uint(r1);
    unsigned q0 = v0 & 0xFFFF0000u, q1 = v1 & 0xFFFF0000u;
    float s0 = r0 - __uint_as_float(q0);
    float s1 = r1 - __uint_as_float(q1);
    h = (h0 >> 16) | h1;
    m = (q0 >> 16) | q1;
    l = (__float_as_uint(s0) >> 16) | (__float_as_uint(s1) & 0xFFFF0000u);
}

__device__ __forceinline__ void st16(unsigned short* dst, const unsigned* p) {
    uint4 u; u.x = p[0]; u.y = p[1]; u.z = p[2]; u.w = p[3];
    *(uint4*)dst = u;
}

__global__ __launch_bounds__(256) void mgemm_k(
    const float* __restrict__ A, int lda,
    const float* __restrict__ B, int ldb, ll ebB,
    float* __restrict__ C, int ldc,
    const float* __restrict__ bias, int ebBias,
    const float* __restrict__ resid,
    const int* __restrict__ gather,
    const int* __restrict__ gcnt, const int* __restrict__ goff,
    int N, int K, int flags) {
    int e = blockIdx.z;
    int m0, mvalid;
    if (gcnt) {
        int cnt = gcnt[e];
        mvalid = cnt - blockIdx.y * 128;
        if (mvalid <= 0) return;
        if (mvalid > 128) mvalid = 128;
        m0 = goff[e] + blockIdx.y * 128;
    } else {
        m0 = blockIdx.y * 128; mvalid = 128;
    }
    int n0 = blockIdx.x * 128;
    const float* Bp = B + (ll)e * ebB;

    // 6 split planes, 8KB each = 48KB LDS (3 blocks/CU by LDS)
    __shared__ __align__(16) unsigned short Ah[128][32], Amd[128][32], Alo[128][32];
    __shared__ __align__(16) unsigned short Bh[128][32], Bmd[128][32], Blo[128][32];

    int tid = threadIdx.x;
    // staging roles: A = 128 rows x 2 k-halves (16 floats each, float4 loads);
    //                B = 128 cols x 2 k-halves (16 strided scalar loads -> transposed store)
    int arow = tid >> 1, apart = (tid & 1) * 16;
    int asrc = (arow < mvalid) ? arow : 0;
    ll aRowG = gather ? (ll)gather[m0 + asrc] : (ll)(m0 + asrc);
    const float* Ap = A + aRowG * (ll)lda + apart;
    int bn = tid & 127, bkh = (tid >> 7) * 16;
    const float* Bpp = Bp + (ll)bkh * ldb + n0 + bn;

    // compute roles: wave (wid) owns a 64x64 quadrant; 4x4 subtiles of 16x16
    int lane = tid & 63, wid = tid >> 6;
    int wr = (wid >> 1) * 64, wc = (wid & 1) * 64;
    int fr = lane & 15, fk = (lane >> 4) * 8;   // frag row/col + k-offset (16B)

    f32x4 acc[4][4];
    f32x4 zero4 = {0.0f, 0.0f, 0.0f, 0.0f};
#pragma unroll
    for (int i = 0; i < 4; i++)
#pragma unroll
        for (int j = 0; j < 4; j++) acc[i][j] = zero4;

    for (int k0 = 0; k0 < K; k0 += 32) {
        // issue global loads first: latency hides under the pre-write barrier
        const float4* ap4 = (const float4*)(Ap + k0);
        float4 a4[4];
#pragma unroll
        for (int i = 0; i < 4; i++) a4[i] = ap4[i];
        float bbuf[16];
        const float* bp = Bpp + (ll)k0 * ldb;
#pragma unroll
        for (int i = 0; i < 16; i++) bbuf[i] = bp[(ll)i * ldb];

        __syncthreads();   // previous iteration's fragment reads complete

        unsigned ph[8], pm[8], pl[8];
        split2(a4[0].x, a4[0].y, ph[0], pm[0], pl[0]);
        split2(a4[0].z, a4[0].w, ph[1], pm[1], pl[1]);
        split2(a4[1].x, a4[1].y, ph[2], pm[2], pl[2]);
        split2(a4[1].z, a4[1].w, ph[3], pm[3], pl[3]);
        split2(a4[2].x, a4[2].y, ph[4], pm[4], pl[4]);
        split2(a4[2].z, a4[2].w, ph[5], pm[5], pl[5]);
        split2(a4[3].x, a4[3].y, ph[6], pm[6], pl[6]);
        split2(a4[3].z, a4[3].w, ph[7], pm[7], pl[7]);
        st16(&Ah[arow][apart], ph);  st16(&Ah[arow][apart + 8], ph + 4);
        st16(&Amd[arow][apart], pm); st16(&Amd[arow][apart + 8], pm + 4);
        st16(&Alo[arow][apart], pl); st16(&Alo[arow][apart + 8], pl + 4);

        split2(bbuf[0],  bbuf[1],  ph[0], pm[0], pl[0]);
        split2(bbuf[2],  bbuf[3],  ph[1], pm[1], pl[1]);
        split2(bbuf[4],  bbuf[5],  ph[2], pm[2], pl[2]);
        split2(bbuf[6],  bbuf[7],  ph[3], pm[3], pl[3]);
        split2(bbuf[8],  bbuf[9],  ph[4], pm[4], pl[4]);
        split2(bbuf[10], bbuf[11], ph[5], pm[5], pl[5]);
        split2(bbuf[12], bbuf[13], ph[6], pm[6], pl[6]);
        split2(bbuf[14], bbuf[15], ph[7], pm[7], pl[7]);
        st16(&Bh[bn][bkh], ph);  st16(&Bh[bn][bkh + 8], ph + 4);
        st16(&Bmd[bn][bkh], pm); st16(&Bmd[bn][bkh + 8], pm + 4);
        st16(&Blo[bn][bkh], pl); st16(&Blo[bn][bkh + 8], pl + 4);

        __syncthreads();   // tiles visible

        bf16x8 Afh[4], Afm[4], Afl[4];
#pragma unroll
        for (int mi = 0; mi < 4; mi++) {
            int rr = wr + mi * 16 + fr;
            Afh[mi] = *(const bf16x8*)&Ah[rr][fk];
            Afm[mi] = *(const bf16x8*)&Amd[rr][fk];
            Afl[mi] = *(const bf16x8*)&Alo[rr][fk];
        }
#pragma unroll
        for (int ni = 0; ni < 4; ni++) {
            int rc = wc + ni * 16 + fr;
            bf16x8 bh = *(const bf16x8*)&Bh[rc][fk];
            bf16x8 bm = *(const bf16x8*)&Bmd[rc][fk];
            bf16x8 bl = *(const bf16x8*)&Blo[rc][fk];
#pragma unroll
            for (int mi = 0; mi < 4; mi++) {
                f32x4 c = acc[mi][ni];
                c = __builtin_amdgcn_mfma_f32_16x16x32_bf16(Afh[mi], bh, c, 0, 0, 0);
                c = __builtin_amdgcn_mfma_f32_16x16x32_bf16(Afh[mi], bm, c, 0, 0, 0);
                c = __builtin_amdgcn_mfma_f32_16x16x32_bf16(Afm[mi], bh, c, 0, 0, 0);
                c = __builtin_amdgcn_mfma_f32_16x16x32_bf16(Afh[mi], bl, c, 0, 0, 0);
                c = __builtin_amdgcn_mfma_f32_16x16x32_bf16(Afm[mi], bm, c, 0, 0, 0);
                c = __builtin_amdgcn_mfma_f32_16x16x32_bf16(Afl[mi], bh, c, 0, 0, 0);
                acc[mi][ni] = c;
            }
        }
    }

    // epilogue: D[row][col]: col = lane&15, row = 4*(lane>>4)+reg  [m89-verified]
    int frow = (lane >> 4) * 4;
#pragma unroll
    for (int ni = 0; ni < 4; ni++) {
        int j = n0 + wc + ni * 16 + fr;
        float bv = (flags & 1) ? bias[(ll)e * ebBias + j] : 0.0f;
#pragma unroll
        for (int mi = 0; mi < 4; mi++) {
            int ib = wr + mi * 16 + frow;
#pragma unroll
            for (int r = 0; r < 4; r++) {
                int i = ib + r;
                if (i >= mvalid) continue;
                ll gm = (ll)(m0 + i);
                float vv = acc[mi][ni][r] + bv;
                if (flags & 2) {
                    float g = vv;
                    vv = 0.5f * g * (1.0f + tanhf(0.7978845608028654f * (g + 0.044715f * g * g * g)));
                }
                if (flags & 4) vv += resid[gm * ldc + j];
                if (flags & 8) vv += C[gm * ldc + j];
                C[gm * ldc + j] = vv;
            }
        }
    }
}

// ---------------- small-N projection (wave per token) ----------------
__global__ __launch_bounds__(256) void smalln_k(const float* __restrict__ A,
                                                const float* __restrict__ W,
                                                float* __restrict__ Co, int N) {
    int wv = (blockIdx.x * 256 + threadIdx.x) >> 6;
    int lane = threadIdx.x & 63;
    if (wv >= T) return;
    const float* a = A + (ll)wv * Dm;
    float xs[16];
#pragma unroll
    for (int i = 0; i < 16; i++) xs[i] = a[lane + 64 * i];
    for (int n = 0; n < N; n++) {
        float s = 0.0f;
#pragma unroll
        for (int i = 0; i < 16; i++) s = fmaf(xs[i], W[(ll)(lane + 64 * i) * N + n], s);
#pragma unroll
        for (int off = 32; off >= 1; off >>= 1) s += __shfl_xor(s, off);
        if (lane == 0) Co[(ll)wv * N + n] = s;
    }
}

// ---------------- RoPE (q and k in place) ----------------
__global__ __launch_bounds__(256) void rope_k(float* __restrict__ q, float* __restrict__ k) {
    int i = blockIdx.x * 256 + threadIdx.x;   // T*16*32
    int d = i & 31; int h = (i >> 5) & 15; int t = i >> 9;
    float inv = powf(10000.0f, -(float)(2 * d) * (1.0f / 64.0f));
    float ang = (float)t * inv;
    float cs = cosf(ang), sn = sinf(ang);
    ll base = (ll)t * Dm + h * 64 + d;
    float a = q[base], b = q[base + 32];
    q[base] = a * cs - b * sn; q[base + 32] = b * cs + a * sn;
    a = k[base]; b = k[base + 32];
    k[base] = a * cs - b * sn; k[base + 32] = b * cs + a * sn;
}

// ---------------- lightning indexer scores (full TxT, unmasked) ----------------
__global__ __launch_bounds__(256) void idx_k(const float* __restrict__ qi,
                                             const float* __restrict__ ki,
                                             const float* __restrict__ hww,
                                             float* __restrict__ out) {
    __shared__ float Aq[64][65];
    __shared__ float Bk[64][65];
    __shared__ float hs[64][4];
    int t0 = blockIdx.y * 64, s0 = blockIdx.x * 64;
    int tid = threadIdx.x;
    int tx = tid & 15, ty = tid >> 4;
    int ty4 = ty * 4, tx4 = tx * 4;
    if (tid < 64) {
#pragma unroll
        for (int e = 0; e < 4; e++) hs[tid][e] = hww[(ll)(t0 + tid) * 4 + e];
    }
    // ki tile (head-independent), once
#pragma unroll
    for (int it = 0; it < 4; it++) {
        int f4 = tid + it * 256;
        int row = f4 >> 4, c4 = (f4 & 15) * 4;
        float4 kv = *(const float4*)(ki + (ll)(s0 + row) * 64 + c4);
        Bk[row][c4] = kv.x; Bk[row][c4 + 1] = kv.y; Bk[row][c4 + 2] = kv.z; Bk[row][c4 + 3] = kv.w;
    }
    float acc[4][4];
#pragma unroll
    for (int r = 0; r < 4; r++)
#pragma unroll
        for (int c = 0; c < 4; c++) acc[r][c] = 0.0f;

    for (int h = 0; h < 4; h++) {
        __syncthreads();   // prev compute done (and Bk/hs visible on h==0)
#pragma unroll
        for (int it = 0; it < 4; it++) {
            int f4 = tid + it * 256;
            int row = f4 >> 4, c4 = (f4 & 15) * 4;
            float4 qv = *(const float4*)(qi + (ll)(t0 + row) * 256 + h * 64 + c4);
            Aq[row][c4] = qv.x; Aq[row][c4 + 1] = qv.y; Aq[row][c4 + 2] = qv.z; Aq[row][c4 + 3] = qv.w;
        }
        __syncthreads();
        float dh[4][4];
#pragma unroll
        for (int r = 0; r < 4; r++)
#pragma unroll
            for (int c = 0; c < 4; c++) dh[r][c] = 0.0f;
#pragma unroll 8
        for (int d = 0; d < 64; d++) {
            float a0 = Aq[ty4 + 0][d], a1 = Aq[ty4 + 1][d], a2 = Aq[ty4 + 2][d], a3 = Aq[ty4 + 3][d];
            float b0 = Bk[tx4 + 0][d], b1 = Bk[tx4 + 1][d], b2 = Bk[tx4 + 2][d], b3 = Bk[tx4 + 3][d];
            dh[0][0] = fmaf(a0, b0, dh[0][0]); dh[0][1] = fmaf(a0, b1, dh[0][1]);
            dh[0][2] = fmaf(a0, b2, dh[0][2]); dh[0][3] = fmaf(a0, b3, dh[0][3]);
            dh[1][0] = fmaf(a1, b0, dh[1][0]); dh[1][1] = fmaf(a1, b1, dh[1][1]);
            dh[1][2] = fmaf(a1, b2, dh[1][2]); dh[1][3] = fmaf(a1, b3, dh[1][3]);
            dh[2][0] = fmaf(a2, b0, dh[2][0]); dh[2][1] = fmaf(a2, b1, dh[2][1]);
            dh[2][2] = fmaf(a2, b2, dh[2][2]); dh[2][3] = fmaf(a2, b3, dh[2][3]);
            dh[3][0] = fmaf(a3, b0, dh[3][0]); dh[3][1] = fmaf(a3, b1, dh[3][1]);
            dh[3][2] = fmaf(a3, b2, dh[3][2]); dh[3][3] = fmaf(a3, b3, dh[3][3]);
        }
#pragma unroll
        for (int r = 0; r < 4; r++) {
            float hv = hs[ty4 + r][h];
#pragma unroll
            for (int c = 0; c < 4; c++)
                acc[r][c] = fmaf(hv, fmaxf(dh[r][c], 0.0f), acc[r][c]);
        }
    }
#pragma unroll
    for (int r = 0; r < 4; r++)
#pragma unroll
        for (int c = 0; c < 4; c++)
            out[(ll)(t0 + ty4 + r) * T + s0 + tx4 + c] = acc[r][c] * 0.125f;
}

// ---------------- exact top-512 per row: 64-bit radix select ----------------
// key = sortable(float)<<32 | ~col  -> unique keys, lowest-index tie-break
__global__ __launch_bounds__(256) void topk_k(const float* __restrict__ idx,
                                              int* __restrict__ seli,
                                              int* __restrict__ selc) {
    int t = blockIdx.x, tid = threadIdx.x;
    const float* row = idx + (ll)t * T;
    if (t < SPK) {   // all causal entries selected
        for (int s = tid; s <= t; s += 256) seli[(ll)t * SPK + s] = s;
        if (tid == 0) selc[t] = t + 1;
        return;
    }
    __shared__ unsigned int hist[256];
    __shared__ unsigned long long sh_prefix;
    __shared__ int sh_k, sh_cur;
    if (tid == 0) { sh_prefix = 0ULL; sh_k = SPK; sh_cur = 0; }
    for (int p = 7; p >= 0; p--) {
        hist[tid] = 0u;
        __syncthreads();
        unsigned long long prefix = sh_prefix;
        unsigned long long maskhi = (p == 7) ? 0ULL : ((~0ULL) << ((p + 1) * 8));
        for (int s = tid; s <= t; s += 256) {
            unsigned int u = __float_as_uint(row[s]);
            u = (u & 0x80000000u) ? ~u : (u | 0x80000000u);
            unsigned long long key = ((unsigned long long)u << 32) | (unsigned int)(0xFFFFFFFFu - (unsigned int)s);
            if ((key & maskhi) == prefix)
                atomicAdd(&hist[(unsigned int)(key >> (p * 8)) & 0xFFu], 1u);
        }
        __syncthreads();
        if (tid == 0) {
            int rem = sh_k, b;
            for (b = 255; b > 0; b--) {
                int hc = (int)hist[b];
                if (hc >= rem) break;
                rem -= hc;
            }
            sh_prefix = prefix | ((unsigned long long)(unsigned int)b << (p * 8));
            sh_k = rem;
        }
        __syncthreads();
    }
    unsigned long long tau = sh_prefix;
    for (int s = tid; s <= t; s += 256) {
        unsigned int u = __float_as_uint(row[s]);
        u = (u & 0x80000000u) ? ~u : (u | 0x80000000u);
        unsigned long long key = ((unsigned long long)u << 32) | (unsigned int)(0xFFFFFFFFu - (unsigned int)s);
        if (key >= tau) {
            int pos = atomicAdd(&sh_cur, 1);
            seli[(ll)t * SPK + pos] = s;
        }
    }
    __syncthreads();
    if (tid == 0) selc[t] = sh_cur;
}

// ---------------- sparse attention: block per query token, all 16 heads ----------------
__global__ __launch_bounds__(256) void attn_k(const float* __restrict__ q,
                                              const float* __restrict__ k,
                                              const float* __restrict__ v,
                                              const int* __restrict__ seli,
                                              const int* __restrict__ selc,
                                              float* __restrict__ av) {
    int t = blockIdx.x, tid = threadIdx.x;
    __shared__ float qs[1024];
    __shared__ float sc[16 * 513];   // stride 513 kills stride-512 bank conflicts
    __shared__ int ssel[512];
    int n = selc[t];
    ((float4*)qs)[tid] = ((const float4*)(q + (ll)t * Dm))[tid];
    for (int j = tid; j < n; j += 256) ssel[j] = seli[(ll)t * SPK + j];
    __syncthreads();
    int lane = tid & 63, w = tid >> 6;
    int h = lane >> 2, part = lane & 3;
    const float4* qp = (const float4*)(qs + lane * 16);
    float4 q0 = qp[0], q1 = qp[1], q2 = qp[2], q3 = qp[3];
    for (int j = w; j < n; j += 4) {
        int s = ssel[j];
        const float4* kp = (const float4*)(k + (ll)s * Dm + lane * 16);
        float4 k0 = kp[0], k1 = kp[1], k2 = kp[2], k3 = kp[3];
        float d;
        d  = q0.x * k0.x + q0.y * k0.y + q0.z * k0.z + q0.w * k0.w;
        d += q1.x * k1.x + q1.y * k1.y + q1.z * k1.z + q1.w * k1.w;
        d += q2.x * k2.x + q2.y * k2.y + q2.z * k2.z + q2.w * k2.w;
        d += q3.x * k3.x + q3.y * k3.y + q3.z * k3.z + q3.w * k3.w;
        d += __shfl_xor(d, 1);
        d += __shfl_xor(d, 2);
        if (part == 0) sc[h * 513 + j] = d * 0.125f;
    }
    __syncthreads();
    for (int hh = w * 4; hh < w * 4 + 4; hh++) {
        float m = -3.0e38f;
        for (int j = lane; j < n; j += 64) m = fmaxf(m, sc[hh * 513 + j]);
#pragma unroll
        for (int off = 32; off >= 1; off >>= 1) m = fmaxf(m, __shfl_xor(m, off));
        float ssum = 0.0f;
        for (int j = lane; j < n; j += 64) {
            float p = expf(sc[hh * 513 + j] - m);
            sc[hh * 513 + j] = p; ssum += p;
        }
#pragma unroll
        for (int off = 32; off >= 1; off >>= 1) ssum += __shfl_xor(ssum, off);
        float inv = 1.0f / ssum;
        for (int j = lane; j < n; j += 64) sc[hh * 513 + j] *= inv;
    }
    __syncthreads();
    int base = tid * 4, oh = tid >> 4;
    float ax = 0, ay = 0, az = 0, aw = 0;
    for (int j = 0; j < n; j++) {
        float p = sc[oh * 513 + j];
        float4 vv = *(const float4*)(v + (ll)ssel[j] * Dm + base);
        ax = fmaf(p, vv.x, ax); ay = fmaf(p, vv.y, ay);
        az = fmaf(p, vv.z, az); aw = fmaf(p, vv.w, aw);
    }
    float4 o4; o4.x = ax; o4.y = ay; o4.z = az; o4.w = aw;
    *(float4*)(av + (ll)t * Dm + base) = o4;
}

// ---------------- router: softmax + top2 + aux accumulators ----------------
__global__ __launch_bounds__(256) void router_k(const float* __restrict__ x2n,
                                                const float* __restrict__ rw,
                                                const float* __restrict__ rb,
                                                float* __restrict__ probs,
                                                float* __restrict__ gates,
                                                int* __restrict__ topi,
                                                int* __restrict__ cnt,
                                                float* __restrict__ psum) {
    int wv = (blockIdx.x * 256 + threadIdx.x) >> 6;
    int lane = threadIdx.x & 63;
    if (wv >= T) return;
    const float* a = x2n + (ll)wv * Dm;
    float l[8] = {0, 0, 0, 0, 0, 0, 0, 0};
    for (int i = 0; i < 16; i++) {
        int kk = lane + 64 * i;
        float xk = a[kk];
        const float* rp = rw + (ll)kk * 8;
#pragma unroll
        for (int e = 0; e < 8; e++) l[e] = fmaf(xk, rp[e], l[e]);
    }
#pragma unroll
    for (int e = 0; e < 8; e++) {
#pragma unroll
        for (int off = 32; off >= 1; off >>= 1) l[e] += __shfl_xor(l[e], off);
    }
    if (lane == 0) {
        float m = -3.0e38f;
#pragma unroll
        for (int e = 0; e < 8; e++) { l[e] += rb[e]; m = fmaxf(m, l[e]); }
        float p[8], s = 0.0f;
#pragma unroll
        for (int e = 0; e < 8; e++) { p[e] = expf(l[e] - m); s += p[e]; }
        float invs = 1.0f / s;
#pragma unroll
        for (int e = 0; e < 8; e++) {
            p[e] *= invs;
            probs[(ll)wv * 8 + e] = p[e];
            atomicAdd(&psum[e], p[e]);
        }
        int i1 = 0; float v1 = p[0];
#pragma unroll
        for (int e = 1; e < 8; e++) if (p[e] > v1) { v1 = p[e]; i1 = e; }
        int i2 = -1; float v2 = -1.0f;
#pragma unroll
        for (int e = 0; e < 8; e++) if (e != i1 && p[e] > v2) { v2 = p[e]; i2 = e; }
        float g = 1.0f / (v1 + v2);
        gates[wv * 2] = v1 * g; gates[wv * 2 + 1] = v2 * g;
        topi[wv * 2] = i1; topi[wv * 2 + 1] = i2;
        atomicAdd(&cnt[i1], 1); atomicAdd(&cnt[i2], 1);
    }
}

__global__ void offs_k(const int* __restrict__ cnt, int* __restrict__ offs) {
    if (threadIdx.x == 0 && blockIdx.x == 0) {
        int o = 0;
        for (int e = 0; e < 8; e++) { offs[e] = o; o += (cnt[e] + 127) & ~127; }
        offs[8] = o;
    }
}

__global__ __launch_bounds__(256) void scatter_k(const int* __restrict__ topi,
                                                 const float* __restrict__ gates,
                                                 const int* __restrict__ offs,
                                                 int* __restrict__ curs,
                                                 int* __restrict__ ptok,
                                                 float* __restrict__ pgate,
                                                 int* __restrict__ tokp) {
    int tk = blockIdx.x * 256 + threadIdx.x;
    if (tk >= T) return;
    for (int j = 0; j < 2; j++) {
        int e = topi[tk * 2 + j];
        int slot = atomicAdd(&curs[e], 1);
        int idx = offs[e] + slot;
        ptok[idx] = tk;
        pgate[idx] = gates[tk * 2 + j];
        tokp[tk * 2 + j] = idx;
    }
}

__global__ __launch_bounds__(256) void combine_k(const float* __restrict__ x1,
                                                 const float* __restrict__ y,
                                                 const int* __restrict__ tokp,
                                                 const float* __restrict__ pgate,
                                                 float* __restrict__ out) {
    int i = blockIdx.x * 256 + threadIdx.x;   // T*Dm/4
    int tk = i >> 8, d4 = i & 255;
    int p0 = tokp[tk * 2], p1 = tokp[tk * 2 + 1];
    float g0 = pgate[p0], g1 = pgate[p1];
    float4 a = ((const float4*)(x1 + (ll)tk * Dm))[d4];
    float4 y0 = ((const float4*)(y + (ll)p0 * Dm))[d4];
    float4 y1 = ((const float4*)(y + (ll)p1 * Dm))[d4];
    float4 o4;
    o4.x = a.x + g0 * y0.x + g1 * y1.x;
    o4.y = a.y + g0 * y0.y + g1 * y1.y;
    o4.z = a.z + g0 * y0.z + g1 * y1.z;
    o4.w = a.w + g0 * y0.w + g1 * y1.w;
    ((float4*)(out + (ll)tk * Dm))[d4] = o4;
}

__global__ void aux_k(const int* __restrict__ cnt, const float* __restrict__ psum,
                      float* __restrict__ outp) {
    if (threadIdx.x == 0 && blockIdx.x == 0) {
        float s = 0.0f;
        for (int e = 0; e < 8; e++) s += (float)cnt[e] * psum[e];
        outp[0] = 8.0f * s * (1.0f / (2048.0f * 2048.0f));
    }
}

// ---------------- launch ----------------
extern "C" void kernel_launch(void* const* d_in, const int* in_sizes, int n_in,
                              void* d_out, int out_size, void* d_ws, size_t ws_size,
                              hipStream_t stream) {
    const float* x      = (const float*)d_in[0];
    const float* n1w    = (const float*)d_in[1];
    const float* n2w    = (const float*)d_in[2];
    const float* wq_idx = (const float*)d_in[3];
    const float* wk_idx = (const float*)d_in[4];
    const float* w_head = (const float*)d_in[5];
    const float* wq     = (const float*)d_in[6];
    const float* wk     = (const float*)d_in[7];
    const float* wvp    = (const float*)d_in[8];
    const float* wo     = (const float*)d_in[9];
    const float* rw     = (const float*)d_in[10];
    const float* rb     = (const float*)d_in[11];
    const float* w1     = (const float*)d_in[12];
    const float* b1     = (const float*)d_in[13];
    const float* w2     = (const float*)d_in[14];
    const float* b2     = (const float*)d_in[15];

    float* ws = (float*)d_ws;
    float* out  = (float*)d_out;               // [T*Dm]
    float* auxp = out + (ll)T * Dm;            // [1]
    float* idxs = auxp + 1;                    // [T*T]

    float* xn   = ws + OFF_XN;
    float* qb   = ws + OFF_Q;
    float* kb   = ws + OFF_K;
    float* vb   = ws + OFF_V;
    float* av   = ws + OFF_AV;
    float* x1   = ws + OFF_X1;
    float* x2n  = ws + OFF_X2N;
    float* qi   = ws + OFF_QI;
    float* kib  = ws + OFF_KI;
    float* hwb  = ws + OFF_HW;
    float* probs = ws + OFF_PROBS;
    float* gates = ws + OFF_GATES;
    int*   topi  = (int*)(ws + OFF_TOPI);
    int*   ptok  = (int*)(ws + OFF_PTOK);
    float* pgate = ws + OFF_PGATE;
    int*   tokp  = (int*)(ws + OFF_TOKP);
    int*   cnt   = (int*)(ws + OFF_CNT);
    float* psum  = ws + OFF_PSUM;
    int*   offs  = (int*)(ws + OFF_OFFS);
    int*   curs  = (int*)(ws + OFF_CURS);
    int*   seli  = (int*)(ws + OFF_SELI);
    int*   selc  = (int*)(ws + OFF_SELC);
    float* hmid  = ws + OFF_HMID;   // aliases q..  (dead by MoE)
    float* yb    = ws + OFF_Y;      // aliases k/v/av (dead by MoE)

    // zero the small counter block (cnt, psum, offs, curs)
    hipMemsetAsync(ws + OFF_CNT, 0, 256, stream);

    // --- norm1 ---
    rmsnorm_k<<<T, 256, 0, stream>>>(x, n1w, xn);
    // --- indexer projections (OLD fp32 kernel: keep top-512 selection bit-stable) ---
    gemm_k<<<dim3(4, 16, 1), 256, 0, stream>>>(xn, Dm, wq_idx, 256, 0, qi, 256,
        nullptr, 0, nullptr, nullptr, nullptr, nullptr, 256, Dm, 0);
    gemm_k<<<dim3(1, 16, 1), 256, 0, stream>>>(xn, Dm, wk_idx, 64, 0, kib, 64,
        nullptr, 0, nullptr, nullptr, nullptr, nullptr, 64, Dm, 0);
    smalln_k<<<T / 4, 256, 0, stream>>>(xn, w_head, hwb, 4);
    // --- QKV (MFMA split GEMM) ---
    mgemm_k<<<dim3(8, 16, 1), 256, 0, stream>>>(xn, Dm, wq, Dm, 0, qb, Dm,
        nullptr, 0, nullptr, nullptr, nullptr, nullptr, Dm, Dm, 0);
    mgemm_k<<<dim3(8, 16, 1), 256, 0, stream>>>(xn, Dm, wk, Dm, 0, kb, Dm,
        nullptr, 0, nullptr, nullptr, nullptr, nullptr, Dm, Dm, 0);
    mgemm_k<<<dim3(8, 16, 1), 256, 0, stream>>>(xn, Dm, wvp, Dm, 0, vb, Dm,
        nullptr, 0, nullptr, nullptr, nullptr, nullptr, Dm, Dm, 0);
    rope_k<<<4096, 256, 0, stream>>>(qb, kb);
    // --- indexer scores (full, unmasked -> output) + top-512 ---
    idx_k<<<dim3(32, 32, 1), 256, 0, stream>>>(qi, kib, hwb, idxs);
    topk_k<<<T, 256, 0, stream>>>(idxs, seli, selc);
    // --- sparse attention ---
    attn_k<<<T, 256, 0, stream>>>(qb, kb, vb, seli, selc, av);
    // --- wo + residual ---
    mgemm_k<<<dim3(8, 16, 1), 256, 0, stream>>>(av, Dm, wo, Dm, 0, x1, Dm,
        nullptr, 0, x, nullptr, nullptr, nullptr, Dm, Dm, 4);
    // --- norm2 + router ---
    rmsnorm_k<<<T, 256, 0, stream>>>(x1, n2w, x2n);
    router_k<<<T / 4, 256, 0, stream>>>(x2n, rw, rb, probs, gates, topi, cnt, psum);
    offs_k<<<1, 64, 0, stream>>>(cnt, offs);
    scatter_k<<<T / 256, 256, 0, stream>>>(topi, gates, offs, curs, ptok, pgate, tokp);
    // --- MoE: 8 DFF chunks of 512, grouped MFMA GEMMs ---
    for (int c = 0; c < DFF / MOE_CH; c++) {
        // hmid = gelu(x2n[gather] @ w1[e][:, c*512 .. ] + b1)
        mgemm_k<<<dim3(MOE_CH / 128, 16, 8), 256, 0, stream>>>(
            x2n, Dm, w1 + c * MOE_CH, DFF, (ll)Dm * DFF, hmid, MOE_CH,
            b1 + c * MOE_CH, DFF, nullptr, ptok, cnt, offs, MOE_CH, Dm, 3);
        // y (+)= hmid @ w2[e][c*512 .. , :]  (+ b2 on first chunk)
        mgemm_k<<<dim3(Dm / 128, 16, 8), 256, 0, stream>>>(
            hmid, MOE_CH, w2 + (ll)c * MOE_CH * Dm, Dm, (ll)DFF * Dm, yb, Dm,
            b2, Dm, nullptr, nullptr, cnt, offs, Dm, MOE_CH, (c == 0) ? 1 : 8);
    }
    // --- combine + aux ---
    combine_k<<<T * Dm / 4 / 256, 256, 0, stream>>>(x1, yb, tokp, pgate, out);
    aux_k<<<1, 64, 0, stream>>>(cnt, psum, auxp);
}

// Round 2
// 2355.123 us; speedup vs baseline: 2.1534x; 1.4196x over previous
//
#include <hip/hip_runtime.h>

typedef long long ll;
typedef __bf16 bf16x8 __attribute__((ext_vector_type(8)));
typedef float f32x4 __attribute__((ext_vector_type(4)));

#define T 2048
#define Dm 1024
#define DFF 4096
#define SPK 512
#define MOE_CH 1024   // DFF chunk for MoE staging (4 chunks)

// ---------------- workspace offsets (in floats) ----------------
// Live ranges: xn,q,k,v,av die before MoE; hmid/y alias them.
static const ll OFF_XN    = 0;          // 2048*1024
static const ll OFF_Q     = 2097152;    // 2048*1024
static const ll OFF_K     = 4194304;    // 2048*1024
static const ll OFF_V     = 6291456;    // 2048*1024
static const ll OFF_AV    = 8388608;    // 2048*1024
static const ll OFF_X1    = 10485760;   // 2048*1024  (live to the end)
static const ll OFF_X2N   = 12582912;   // 2048*1024  (live through MoE GEMM1)
static const ll OFF_QI    = 14680064;   // 2048*256
static const ll OFF_KI    = 15204352;   // 2048*64
static const ll OFF_HW    = 15335424;   // 2048*4
static const ll OFF_PROBS = 15343616;   // 2048*8
static const ll OFF_GATES = 15360000;   // 2048*2
static const ll OFF_TOPI  = 15364096;   // 2048*2 int
static const ll OFF_PTOK  = 15368192;   // 5120 int
static const ll OFF_PGATE = 15373312;   // 5120
static const ll OFF_TOKP  = 15378432;   // 2048*2 int
static const ll OFF_CNT   = 15382528;   // 8 int   -- memset-0 region starts here
static const ll OFF_PSUM  = 15382536;   // 8 float
static const ll OFF_OFFS  = 15382544;   // 9 int
static const ll OFF_CURS  = 15382560;   // 8 int   -- memset-0 region = 64 floats
static const ll OFF_SELI  = 15382592;   // 2048*512 int
static const ll OFF_SELC  = 16431168;   // 2048 int
// total ws = 16433216 floats = ~62.7 MiB
// MoE aliases (xn, q, k, v, av all dead by MoE):
static const ll OFF_HMID  = 0;          // 5120*1024 -> ends 5242880
static const ll OFF_Y     = 5242880;    // 5120*1024 -> ends 10485760 (= OFF_X1)

// ---------------- RMSNorm ----------------
__global__ __launch_bounds__(256) void rmsnorm_k(const float* __restrict__ x,
                                                 const float* __restrict__ w,
                                                 float* __restrict__ o) {
    int t = blockIdx.x, tid = threadIdx.x;
    __shared__ float red[4];
    float4 xv = ((const float4*)(x + (ll)t * Dm))[tid];
    float ss = xv.x * xv.x + xv.y * xv.y + xv.z * xv.z + xv.w * xv.w;
#pragma unroll
    for (int off = 32; off >= 1; off >>= 1) ss += __shfl_xor(ss, off);
    int lane = tid & 63, wv = tid >> 6;
    if (lane == 0) red[wv] = ss;
    __syncthreads();
    float tot = red[0] + red[1] + red[2] + red[3];
    float sc = 1.0f / sqrtf(tot * (1.0f / 1024.0f) + 1e-6f);
    float4 wv4 = ((const float4*)w)[tid];
    float4 ov;
    ov.x = xv.x * sc * wv4.x; ov.y = xv.y * sc * wv4.y;
    ov.z = xv.z * sc * wv4.z; ov.w = xv.w * sc * wv4.w;
    ((float4*)(o + (ll)t * Dm))[tid] = ov;
}

// ---------------- generic tiled fp32 GEMM (kept for indexer path: bit-stable) ----------------
// C[m][n] = A[m][:] @ B[:][n], tile 128x64, BK=8, 256 thr, 8x4 per thread.
// flags: 1=+bias  2=gelu(tanh)  4=+resid[m][n] (ld=ldc)  8=accumulate into C
__global__ __launch_bounds__(256) void gemm_k(
    const float* __restrict__ A, int lda,
    const float* __restrict__ B, int ldb, ll ebB,
    float* __restrict__ C, int ldc,
    const float* __restrict__ bias, int ebBias,
    const float* __restrict__ resid,
    const int* __restrict__ gather,
    const int* __restrict__ gcnt, const int* __restrict__ goff,
    int N, int K, int flags) {
    int e = blockIdx.z;
    int m0, mvalid;
    if (gcnt) {
        int cnt = gcnt[e];
        mvalid = cnt - blockIdx.y * 128;
        if (mvalid <= 0) return;
        if (mvalid > 128) mvalid = 128;
        m0 = goff[e] + blockIdx.y * 128;
    } else {
        m0 = blockIdx.y * 128; mvalid = 128;
    }
    int n0 = blockIdx.x * 64;
    const float* Bp = B + (ll)e * ebB;
    __shared__ float As[8][132];   // +4 pad: 16B-aligned rows, conflict-free
    __shared__ float Bs[8][64];
    int tid = threadIdx.x;
    int tx = tid & 15, ty = tid >> 4;
    int arow = tid >> 1, ak = (tid & 1) * 4;
    int brow = tid >> 4, bn = (tid & 15) * 4;   // only tid<128 loads B
    ll aRow;
    int asrc = (arow < mvalid) ? arow : 0;
    if (gather) aRow = gather[m0 + asrc]; else aRow = m0 + asrc;
    const float* Aptr = A + aRow * (ll)lda + ak;
    bool bin = (tid < 128) && ((n0 + bn) < N);
    const float* Bptr0 = Bp + n0 + bn;
    float acc[8][4];
#pragma unroll
    for (int r = 0; r < 8; r++)
#pragma unroll
        for (int c = 0; c < 4; c++) acc[r][c] = 0.0f;

    for (int k0 = 0; k0 < K; k0 += 8) {
        float4 a4 = *(const float4*)(Aptr + k0);
        float4 b4 = make_float4(0.f, 0.f, 0.f, 0.f);
        if (bin) b4 = *(const float4*)(Bptr0 + (ll)(k0 + brow) * ldb);
        As[ak + 0][arow] = a4.x; As[ak + 1][arow] = a4.y;
        As[ak + 2][arow] = a4.z; As[ak + 3][arow] = a4.w;
        if (tid < 128) *(float4*)&Bs[brow][bn] = b4;
        __syncthreads();
#pragma unroll
        for (int kk = 0; kk < 8; kk++) {
            float4 a0 = *(const float4*)&As[kk][ty * 8];
            float4 a1 = *(const float4*)&As[kk][ty * 8 + 4];
            float4 b0 = *(const float4*)&Bs[kk][tx * 4];
            float aa[8] = {a0.x, a0.y, a0.z, a0.w, a1.x, a1.y, a1.z, a1.w};
            float bb[4] = {b0.x, b0.y, b0.z, b0.w};
#pragma unroll
            for (int r = 0; r < 8; r++)
#pragma unroll
                for (int c = 0; c < 4; c++)
                    acc[r][c] = fmaf(aa[r], bb[c], acc[r][c]);
        }
        __syncthreads();
    }
#pragma unroll
    for (int r = 0; r < 8; r++) {
        int i = ty * 8 + r;
        if (i >= mvalid) continue;
        ll gm = (ll)(m0 + i);
#pragma unroll
        for (int c = 0; c < 4; c++) {
            int j = n0 + tx * 4 + c;
            if (j >= N) continue;
            float vv = acc[r][c];
            if (flags & 1) vv += bias[(ll)e * ebBias + j];
            if (flags & 2) {
                float g = vv;
                vv = 0.5f * g * (1.0f + tanhf(0.7978845608028654f * (g + 0.044715f * g * g * g)));
            }
            if (flags & 4) vv += resid[gm * ldc + j];
            if (flags & 8) vv += C[gm * ldc + j];
            C[gm * ldc + j] = vv;
        }
    }
}

// ---------------- fp32-accurate MFMA GEMM via bf16 truncation split ----------------
// NS=3: a = ah+am+al, 6 products (hh,hm,mh,hl,mm,lh) -> rel err ~2^-22 (selection-safe)
// NS=2: a = ah+am,    3 products (hh,hm,mh)          -> rel err ~3*2^-16 (additive paths)
// Tile 128x128, BK=32, 256 thr (4 waves of 64x64).
// Requires: N % 128 == 0, K % 32 == 0, (non-grouped) M % 128 == 0.
// Multi-B mode (non-grouped, B2!=null): blockIdx.z selects B/B2/B3, C += z*ebC.
// flags identical to gemm_k.
__device__ __forceinline__ void split2(float x0, float x1,
                                       unsigned& h, unsigned& m, unsigned& l) {
    unsigned u0 = __float_as_uint(x0), u1 = __float_as_uint(x1);
    unsigned h0 = u0 & 0xFFFF0000u, h1 = u1 & 0xFFFF0000u;
    float r0 = x0 - __uint_as_float(h0);
    float r1 = x1 - __uint_as_float(h1);
    unsigned v0 = __float_as_uint(r0), v1 = __float_as_uint(r1);
    unsigned q0 = v0 & 0xFFFF0000u, q1 = v1 & 0xFFFF0000u;
    float s0 = r0 - __uint_as_float(q0);
    float s1 = r1 - __uint_as_float(q1);
    h = (h0 >> 16) | h1;
    m = (q0 >> 16) | q1;
    l = (__float_as_uint(s0) >> 16) | (__float_as_uint(s1) & 0xFFFF0000u);
}

__device__ __forceinline__ void st16(unsigned short* dst, const unsigned* p) {
    uint4 u; u.x = p[0]; u.y = p[1]; u.z = p[2]; u.w = p[3];
    *(uint4*)dst = u;
}

template<int NS>
__global__ __launch_bounds__(256) void mgemm_k(
    const float* __restrict__ A, int lda,
    const float* __restrict__ B, int ldb, ll ebB,
    const float* __restrict__ B2, const float* __restrict__ B3, ll ebC,
    float* __restrict__ C, int ldc,
    const float* __restrict__ bias, int ebBias,
    const float* __restrict__ resid,
    const int* __restrict__ gather,
    const int* __restrict__ gcnt, const int* __restrict__ goff,
    int N, int K, int flags) {
    int e = blockIdx.z;
    int m0, mvalid;
    const float* Bp;
    float* Cp = C;
    if (gcnt) {
        int cnt = gcnt[e];
        mvalid = cnt - blockIdx.y * 128;
        if (mvalid <= 0) return;
        if (mvalid > 128) mvalid = 128;
        m0 = goff[e] + blockIdx.y * 128;
        Bp = B + (ll)e * ebB;
    } else {
        m0 = blockIdx.y * 128; mvalid = 128;
        Bp = (B2 == nullptr || e == 0) ? B : (e == 1 ? B2 : B3);
        Cp = C + (ll)e * ebC;
    }
    int n0 = blockIdx.x * 128;

    // split planes, 8KB each: NS=3 -> 48KB LDS, NS=2 -> 32KB
    __shared__ __align__(16) unsigned short Ah[128][32], Amd[128][32];
    __shared__ __align__(16) unsigned short Bh[128][32], Bmd[128][32];
    __shared__ __align__(16) unsigned short Alo[NS == 3 ? 128 : 1][32];
    __shared__ __align__(16) unsigned short Blo[NS == 3 ? 128 : 1][32];

    int tid = threadIdx.x;
    // staging roles: A = 128 rows x 2 k-halves (16 floats each, float4 loads);
    //                B = 128 cols x 2 k-halves (16 strided scalar loads -> transposed store)
    int arow = tid >> 1, apart = (tid & 1) * 16;
    int asrc = (arow < mvalid) ? arow : 0;
    ll aRowG = gather ? (ll)gather[m0 + asrc] : (ll)(m0 + asrc);
    const float* Ap = A + aRowG * (ll)lda + apart;
    int bn = tid & 127, bkh = (tid >> 7) * 16;
    const float* Bpp = Bp + (ll)bkh * ldb + n0 + bn;

    // compute roles: wave (wid) owns a 64x64 quadrant; 4x4 subtiles of 16x16
    int lane = tid & 63, wid = tid >> 6;
    int wr = (wid >> 1) * 64, wc = (wid & 1) * 64;
    int fr = lane & 15, fk = (lane >> 4) * 8;   // frag row/col + k-offset (16B)

    f32x4 acc[4][4];
    f32x4 zero4 = {0.0f, 0.0f, 0.0f, 0.0f};
#pragma unroll
    for (int i = 0; i < 4; i++)
#pragma unroll
        for (int j = 0; j < 4; j++) acc[i][j] = zero4;

    for (int k0 = 0; k0 < K; k0 += 32) {
        // issue global loads first: latency hides under the pre-write barrier
        const float4* ap4 = (const float4*)(Ap + k0);
        float4 a4[4];
#pragma unroll
        for (int i = 0; i < 4; i++) a4[i] = ap4[i];
        float bbuf[16];
        const float* bp = Bpp + (ll)k0 * ldb;
#pragma unroll
        for (int i = 0; i < 16; i++) bbuf[i] = bp[(ll)i * ldb];

        __syncthreads();   // previous iteration's fragment reads complete

        unsigned ph[8], pm[8], pl[8];
        split2(a4[0].x, a4[0].y, ph[0], pm[0], pl[0]);
        split2(a4[0].z, a4[0].w, ph[1], pm[1], pl[1]);
        split2(a4[1].x, a4[1].y, ph[2], pm[2], pl[2]);
        split2(a4[1].z, a4[1].w, ph[3], pm[3], pl[3]);
        split2(a4[2].x, a4[2].y, ph[4], pm[4], pl[4]);
        split2(a4[2].z, a4[2].w, ph[5], pm[5], pl[5]);
        split2(a4[3].x, a4[3].y, ph[6], pm[6], pl[6]);
        split2(a4[3].z, a4[3].w, ph[7], pm[7], pl[7]);
        st16(&Ah[arow][apart], ph);  st16(&Ah[arow][apart + 8], ph + 4);
        st16(&Amd[arow][apart], pm); st16(&Amd[arow][apart + 8], pm + 4);
        if constexpr (NS == 3) {
            st16(&Alo[arow][apart], pl); st16(&Alo[arow][apart + 8], pl + 4);
        }

        split2(bbuf[0],  bbuf[1],  ph[0], pm[0], pl[0]);
        split2(bbuf[2],  bbuf[3],  ph[1], pm[1], pl[1]);
        split2(bbuf[4],  bbuf[5],  ph[2], pm[2], pl[2]);
        split2(bbuf[6],  bbuf[7],  ph[3], pm[3], pl[3]);
        split2(bbuf[8],  bbuf[9],  ph[4], pm[4], pl[4]);
        split2(bbuf[10], bbuf[11], ph[5], pm[5], pl[5]);
        split2(bbuf[12], bbuf[13], ph[6], pm[6], pl[6]);
        split2(bbuf[14], bbuf[15], ph[7], pm[7], pl[7]);
        st16(&Bh[bn][bkh], ph);  st16(&Bh[bn][bkh + 8], ph + 4);
        st16(&Bmd[bn][bkh], pm); st16(&Bmd[bn][bkh + 8], pm + 4);
        if constexpr (NS == 3) {
            st16(&Blo[bn][bkh], pl); st16(&Blo[bn][bkh + 8], pl + 4);
        }

        __syncthreads();   // tiles visible

        bf16x8 Afh[4], Afm[4], Afl[4];
#pragma unroll
        for (int mi = 0; mi < 4; mi++) {
            int rr = wr + mi * 16 + fr;
            Afh[mi] = *(const bf16x8*)&Ah[rr][fk];
            Afm[mi] = *(const bf16x8*)&Amd[rr][fk];
            if constexpr (NS == 3) Afl[mi] = *(const bf16x8*)&Alo[rr][fk];
        }
#pragma unroll
        for (int ni = 0; ni < 4; ni++) {
            int rc = wc + ni * 16 + fr;
            bf16x8 bh = *(const bf16x8*)&Bh[rc][fk];
            bf16x8 bm = *(const bf16x8*)&Bmd[rc][fk];
            if constexpr (NS == 3) {
                bf16x8 bl = *(const bf16x8*)&Blo[rc][fk];
#pragma unroll
                for (int mi = 0; mi < 4; mi++) {
                    f32x4 c = acc[mi][ni];
                    c = __builtin_amdgcn_mfma_f32_16x16x32_bf16(Afh[mi], bh, c, 0, 0, 0);
                    c = __builtin_amdgcn_mfma_f32_16x16x32_bf16(Afh[mi], bm, c, 0, 0, 0);
                    c = __builtin_amdgcn_mfma_f32_16x16x32_bf16(Afm[mi], bh, c, 0, 0, 0);
                    c = __builtin_amdgcn_mfma_f32_16x16x32_bf16(Afh[mi], bl, c, 0, 0, 0);
                    c = __builtin_amdgcn_mfma_f32_16x16x32_bf16(Afm[mi], bm, c, 0, 0, 0);
                    c = __builtin_amdgcn_mfma_f32_16x16x32_bf16(Afl[mi], bh, c, 0, 0, 0);
                    acc[mi][ni] = c;
                }
            } else {
#pragma unroll
                for (int mi = 0; mi < 4; mi++) {
                    f32x4 c = acc[mi][ni];
                    c = __builtin_amdgcn_mfma_f32_16x16x32_bf16(Afh[mi], bh, c, 0, 0, 0);
                    c = __builtin_amdgcn_mfma_f32_16x16x32_bf16(Afh[mi], bm, c, 0, 0, 0);
                    c = __builtin_amdgcn_mfma_f32_16x16x32_bf16(Afm[mi], bh, c, 0, 0, 0);
                    acc[mi][ni] = c;
                }
            }
        }
    }

    // epilogue: D[row][col]: col = lane&15, row = 4*(lane>>4)+reg  [m89-verified]
    int frow = (lane >> 4) * 4;
#pragma unroll
    for (int ni = 0; ni < 4; ni++) {
        int j = n0 + wc + ni * 16 + fr;
        float bv = (flags & 1) ? bias[(ll)e * ebBias + j] : 0.0f;
#pragma unroll
        for (int mi = 0; mi < 4; mi++) {
            int ib = wr + mi * 16 + frow;
#pragma unroll
            for (int r = 0; r < 4; r++) {
                int i = ib + r;
                if (i >= mvalid) continue;
                ll gm = (ll)(m0 + i);
                float vv = acc[mi][ni][r] + bv;
                if (flags & 2) {
                    float g = vv;
                    vv = 0.5f * g * (1.0f + tanhf(0.7978845608028654f * (g + 0.044715f * g * g * g)));
                }
                if (flags & 4) vv += resid[gm * ldc + j];
                if (flags & 8) vv += Cp[gm * ldc + j];
                Cp[gm * ldc + j] = vv;
            }
        }
    }
}

// ---------------- small-N projection (wave per token) ----------------
__global__ __launch_bounds__(256) void smalln_k(const float* __restrict__ A,
                                                const float* __restrict__ W,
                                                float* __restrict__ Co, int N) {
    int wv = (blockIdx.x * 256 + threadIdx.x) >> 6;
    int lane = threadIdx.x & 63;
    if (wv >= T) return;
    const float* a = A + (ll)wv * Dm;
    float xs[16];
#pragma unroll
    for (int i = 0; i < 16; i++) xs[i] = a[lane + 64 * i];
    for (int n = 0; n < N; n++) {
        float s = 0.0f;
#pragma unroll
        for (int i = 0; i < 16; i++) s = fmaf(xs[i], W[(ll)(lane + 64 * i) * N + n], s);
#pragma unroll
        for (int off = 32; off >= 1; off >>= 1) s += __shfl_xor(s, off);
        if (lane == 0) Co[(ll)wv * N + n] = s;
    }
}

// ---------------- RoPE (q and k in place) ----------------
__global__ __launch_bounds__(256) void rope_k(float* __restrict__ q, float* __restrict__ k) {
    int i = blockIdx.x * 256 + threadIdx.x;   // T*16*32
    int d = i & 31; int h = (i >> 5) & 15; int t = i >> 9;
    float inv = powf(10000.0f, -(float)(2 * d) * (1.0f / 64.0f));
    float ang = (float)t * inv;
    float cs = cosf(ang), sn = sinf(ang);
    ll base = (ll)t * Dm + h * 64 + d;
    float a = q[base], b = q[base + 32];
    q[base] = a * cs - b * sn; q[base + 32] = b * cs + a * sn;
    a = k[base]; b = k[base + 32];
    k[base] = a * cs - b * sn; k[base + 32] = b * cs + a * sn;
}

// ---------------- lightning indexer scores (full TxT, unmasked) ----------------
__global__ __launch_bounds__(256) void idx_k(const float* __restrict__ qi,
                                             const float* __restrict__ ki,
                                             const float* __restrict__ hww,
                                             float* __restrict__ out) {
    __shared__ float Aq[64][65];
    __shared__ float Bk[64][65];
    __shared__ float hs[64][4];
    int t0 = blockIdx.y * 64, s0 = blockIdx.x * 64;
    int tid = threadIdx.x;
    int tx = tid & 15, ty = tid >> 4;
    int ty4 = ty * 4, tx4 = tx * 4;
    if (tid < 64) {
#pragma unroll
        for (int e = 0; e < 4; e++) hs[tid][e] = hww[(ll)(t0 + tid) * 4 + e];
    }
    // ki tile (head-independent), once
#pragma unroll
    for (int it = 0; it < 4; it++) {
        int f4 = tid + it * 256;
        int row = f4 >> 4, c4 = (f4 & 15) * 4;
        float4 kv = *(const float4*)(ki + (ll)(s0 + row) * 64 + c4);
        Bk[row][c4] = kv.x; Bk[row][c4 + 1] = kv.y; Bk[row][c4 + 2] = kv.z; Bk[row][c4 + 3] = kv.w;
    }
    float acc[4][4];
#pragma unroll
    for (int r = 0; r < 4; r++)
#pragma unroll
        for (int c = 0; c < 4; c++) acc[r][c] = 0.0f;

    for (int h = 0; h < 4; h++) {
        __syncthreads();   // prev compute done (and Bk/hs visible on h==0)
#pragma unroll
        for (int it = 0; it < 4; it++) {
            int f4 = tid + it * 256;
            int row = f4 >> 4, c4 = (f4 & 15) * 4;
            float4 qv = *(const float4*)(qi + (ll)(t0 + row) * 256 + h * 64 + c4);
            Aq[row][c4] = qv.x; Aq[row][c4 + 1] = qv.y; Aq[row][c4 + 2] = qv.z; Aq[row][c4 + 3] = qv.w;
        }
        __syncthreads();
        float dh[4][4];
#pragma unroll
        for (int r = 0; r < 4; r++)
#pragma unroll
            for (int c = 0; c < 4; c++) dh[r][c] = 0.0f;
#pragma unroll 8
        for (int d = 0; d < 64; d++) {
            float a0 = Aq[ty4 + 0][d], a1 = Aq[ty4 + 1][d], a2 = Aq[ty4 + 2][d], a3 = Aq[ty4 + 3][d];
            float b0 = Bk[tx4 + 0][d], b1 = Bk[tx4 + 1][d], b2 = Bk[tx4 + 2][d], b3 = Bk[tx4 + 3][d];
            dh[0][0] = fmaf(a0, b0, dh[0][0]); dh[0][1] = fmaf(a0, b1, dh[0][1]);
            dh[0][2] = fmaf(a0, b2, dh[0][2]); dh[0][3] = fmaf(a0, b3, dh[0][3]);
            dh[1][0] = fmaf(a1, b0, dh[1][0]); dh[1][1] = fmaf(a1, b1, dh[1][1]);
            dh[1][2] = fmaf(a1, b2, dh[1][2]); dh[1][3] = fmaf(a1, b3, dh[1][3]);
            dh[2][0] = fmaf(a2, b0, dh[2][0]); dh[2][1] = fmaf(a2, b1, dh[2][1]);
            dh[2][2] = fmaf(a2, b2, dh[2][2]); dh[2][3] = fmaf(a2, b3, dh[2][3]);
            dh[3][0] = fmaf(a3, b0, dh[3][0]); dh[3][1] = fmaf(a3, b1, dh[3][1]);
            dh[3][2] = fmaf(a3, b2, dh[3][2]); dh[3][3] = fmaf(a3, b3, dh[3][3]);
        }
#pragma unroll
        for (int r = 0; r < 4; r++) {
            float hv = hs[ty4 + r][h];
#pragma unroll
            for (int c = 0; c < 4; c++)
                acc[r][c] = fmaf(hv, fmaxf(dh[r][c], 0.0f), acc[r][c]);
        }
    }
#pragma unroll
    for (int r = 0; r < 4; r++)
#pragma unroll
        for (int c = 0; c < 4; c++)
            out[(ll)(t0 + ty4 + r) * T + s0 + tx4 + c] = acc[r][c] * 0.125f;
}

// ---------------- exact top-512 per row: 64-bit radix select ----------------
// key = sortable(float)<<32 | ~col  -> unique keys, lowest-index tie-break
__global__ __launch_bounds__(256) void topk_k(const float* __restrict__ idx,
                                              int* __restrict__ seli,
                                              int* __restrict__ selc) {
    int t = blockIdx.x, tid = threadIdx.x;
    const float* row = idx + (ll)t * T;
    if (t < SPK) {   // all causal entries selected
        for (int s = tid; s <= t; s += 256) seli[(ll)t * SPK + s] = s;
        if (tid == 0) selc[t] = t + 1;
        return;
    }
    __shared__ unsigned int hist[256];
    __shared__ unsigned long long sh_prefix;
    __shared__ int sh_k, sh_cur;
    if (tid == 0) { sh_prefix = 0ULL; sh_k = SPK; sh_cur = 0; }
    for (int p = 7; p >= 0; p--) {
        hist[tid] = 0u;
        __syncthreads();
        unsigned long long prefix = sh_prefix;
        unsigned long long maskhi = (p == 7) ? 0ULL : ((~0ULL) << ((p + 1) * 8));
        for (int s = tid; s <= t; s += 256) {
            unsigned int u = __float_as_uint(row[s]);
            u = (u & 0x80000000u) ? ~u : (u | 0x80000000u);
            unsigned long long key = ((unsigned long long)u << 32) | (unsigned int)(0xFFFFFFFFu - (unsigned int)s);
            if ((key & maskhi) == prefix)
                atomicAdd(&hist[(unsigned int)(key >> (p * 8)) & 0xFFu], 1u);
        }
        __syncthreads();
        if (tid == 0) {
            int rem = sh_k, b;
            for (b = 255; b > 0; b--) {
                int hc = (int)hist[b];
                if (hc >= rem) break;
                rem -= hc;
            }
            sh_prefix = prefix | ((unsigned long long)(unsigned int)b << (p * 8));
            sh_k = rem;
        }
        __syncthreads();
    }
    unsigned long long tau = sh_prefix;
    for (int s = tid; s <= t; s += 256) {
        unsigned int u = __float_as_uint(row[s]);
        u = (u & 0x80000000u) ? ~u : (u | 0x80000000u);
        unsigned long long key = ((unsigned long long)u << 32) | (unsigned int)(0xFFFFFFFFu - (unsigned int)s);
        if (key >= tau) {
            int pos = atomicAdd(&sh_cur, 1);
            seli[(ll)t * SPK + pos] = s;
        }
    }
    __syncthreads();
    if (tid == 0) selc[t] = sh_cur;
}

// ---------------- sparse attention: block per query token, all 16 heads ----------------
__global__ __launch_bounds__(256) void attn_k(const float* __restrict__ q,
                                              const float* __restrict__ k,
                                              const float* __restrict__ v,
                                              const int* __restrict__ seli,
                                              const int* __restrict__ selc,
                                              float* __restrict__ av) {
    int t = blockIdx.x, tid = threadIdx.x;
    __shared__ float qs[1024];
    __shared__ float sc[16 * 513];   // stride 513 kills stride-512 bank conflicts
    __shared__ int ssel[512];
    int n = selc[t];
    ((float4*)qs)[tid] = ((const float4*)(q + (ll)t * Dm))[tid];
    for (int j = tid; j < n; j += 256) ssel[j] = seli[(ll)t * SPK + j];
    __syncthreads();
    int lane = tid & 63, w = tid >> 6;
    int h = lane >> 2, part = lane & 3;
    const float4* qp = (const float4*)(qs + lane * 16);
    float4 q0 = qp[0], q1 = qp[1], q2 = qp[2], q3 = qp[3];
    for (int j = w; j < n; j += 4) {
        int s = ssel[j];
        const float4* kp = (const float4*)(k + (ll)s * Dm + lane * 16);
        float4 k0 = kp[0], k1 = kp[1], k2 = kp[2], k3 = kp[3];
        float d;
        d  = q0.x * k0.x + q0.y * k0.y + q0.z * k0.z + q0.w * k0.w;
        d += q1.x * k1.x + q1.y * k1.y + q1.z * k1.z + q1.w * k1.w;
        d += q2.x * k2.x + q2.y * k2.y + q2.z * k2.z + q2.w * k2.w;
        d += q3.x * k3.x + q3.y * k3.y + q3.z * k3.z + q3.w * k3.w;
        d += __shfl_xor(d, 1);
        d += __shfl_xor(d, 2);
        if (part == 0) sc[h * 513 + j] = d * 0.125f;
    }
    __syncthreads();
    for (int hh = w * 4; hh < w * 4 + 4; hh++) {
        float m = -3.0e38f;
        for (int j = lane; j < n; j += 64) m = fmaxf(m, sc[hh * 513 + j]);
#pragma unroll
        for (int off = 32; off >= 1; off >>= 1) m = fmaxf(m, __shfl_xor(m, off));
        float ssum = 0.0f;
        for (int j = lane; j < n; j += 64) {
            float p = expf(sc[hh * 513 + j] - m);
            sc[hh * 513 + j] = p; ssum += p;
        }
#pragma unroll
        for (int off = 32; off >= 1; off >>= 1) ssum += __shfl_xor(ssum, off);
        float inv = 1.0f / ssum;
        for (int j = lane; j < n; j += 64) sc[hh * 513 + j] *= inv;
    }
    __syncthreads();
    int base = tid * 4, oh = tid >> 4;
    float ax = 0, ay = 0, az = 0, aw = 0;
    for (int j = 0; j < n; j++) {
        float p = sc[oh * 513 + j];
        float4 vv = *(const float4*)(v + (ll)ssel[j] * Dm + base);
        ax = fmaf(p, vv.x, ax); ay = fmaf(p, vv.y, ay);
        az = fmaf(p, vv.z, az); aw = fmaf(p, vv.w, aw);
    }
    float4 o4; o4.x = ax; o4.y = ay; o4.z = az; o4.w = aw;
    *(float4*)(av + (ll)t * Dm + base) = o4;
}

// ---------------- router: softmax + top2 + aux accumulators ----------------
__global__ __launch_bounds__(256) void router_k(const float* __restrict__ x2n,
                                                const float* __restrict__ rw,
                                                const float* __restrict__ rb,
                                                float* __restrict__ probs,
                                                float* __restrict__ gates,
                                                int* __restrict__ topi,
                                                int* __restrict__ cnt,
                                                float* __restrict__ psum) {
    int wv = (blockIdx.x * 256 + threadIdx.x) >> 6;
    int lane = threadIdx.x & 63;
    if (wv >= T) return;
    const float* a = x2n + (ll)wv * Dm;
    float l[8] = {0, 0, 0, 0, 0, 0, 0, 0};
    for (int i = 0; i < 16; i++) {
        int kk = lane + 64 * i;
        float xk = a[kk];
        const float* rp = rw + (ll)kk * 8;
#pragma unroll
        for (int e = 0; e < 8; e++) l[e] = fmaf(xk, rp[e], l[e]);
    }
#pragma unroll
    for (int e = 0; e < 8; e++) {
#pragma unroll
        for (int off = 32; off >= 1; off >>= 1) l[e] += __shfl_xor(l[e], off);
    }
    if (lane == 0) {
        float m = -3.0e38f;
#pragma unroll
        for (int e = 0; e < 8; e++) { l[e] += rb[e]; m = fmaxf(m, l[e]); }
        float p[8], s = 0.0f;
#pragma unroll
        for (int e = 0; e < 8; e++) { p[e] = expf(l[e] - m); s += p[e]; }
        float invs = 1.0f / s;
#pragma unroll
        for (int e = 0; e < 8; e++) {
            p[e] *= invs;
            probs[(ll)wv * 8 + e] = p[e];
            atomicAdd(&psum[e], p[e]);
        }
        int i1 = 0; float v1 = p[0];
#pragma unroll
        for (int e = 1; e < 8; e++) if (p[e] > v1) { v1 = p[e]; i1 = e; }
        int i2 = -1; float v2 = -1.0f;
#pragma unroll
        for (int e = 0; e < 8; e++) if (e != i1 && p[e] > v2) { v2 = p[e]; i2 = e; }
        float g = 1.0f / (v1 + v2);
        gates[wv * 2] = v1 * g; gates[wv * 2 + 1] = v2 * g;
        topi[wv * 2] = i1; topi[wv * 2 + 1] = i2;
        atomicAdd(&cnt[i1], 1); atomicAdd(&cnt[i2], 1);
    }
}

__global__ void offs_k(const int* __restrict__ cnt, int* __restrict__ offs) {
    if (threadIdx.x == 0 && blockIdx.x == 0) {
        int o = 0;
        for (int e = 0; e < 8; e++) { offs[e] = o; o += (cnt[e] + 127) & ~127; }
        offs[8] = o;
    }
}

__global__ __launch_bounds__(256) void scatter_k(const int* __restrict__ topi,
                                                 const float* __restrict__ gates,
                                                 const int* __restrict__ offs,
                                                 int* __restrict__ curs,
                                                 int* __restrict__ ptok,
                                                 float* __restrict__ pgate,
                                                 int* __restrict__ tokp) {
    int tk = blockIdx.x * 256 + threadIdx.x;
    if (tk >= T) return;
    for (int j = 0; j < 2; j++) {
        int e = topi[tk * 2 + j];
        int slot = atomicAdd(&curs[e], 1);
        int idx = offs[e] + slot;
        ptok[idx] = tk;
        pgate[idx] = gates[tk * 2 + j];
        tokp[tk * 2 + j] = idx;
    }
}

__global__ __launch_bounds__(256) void combine_k(const float* __restrict__ x1,
                                                 const float* __restrict__ y,
                                                 const int* __restrict__ tokp,
                                                 const float* __restrict__ pgate,
                                                 float* __restrict__ out) {
    int i = blockIdx.x * 256 + threadIdx.x;   // T*Dm/4
    int tk = i >> 8, d4 = i & 255;
    int p0 = tokp[tk * 2], p1 = tokp[tk * 2 + 1];
    float g0 = pgate[p0], g1 = pgate[p1];
    float4 a = ((const float4*)(x1 + (ll)tk * Dm))[d4];
    float4 y0 = ((const float4*)(y + (ll)p0 * Dm))[d4];
    float4 y1 = ((const float4*)(y + (ll)p1 * Dm))[d4];
    float4 o4;
    o4.x = a.x + g0 * y0.x + g1 * y1.x;
    o4.y = a.y + g0 * y0.y + g1 * y1.y;
    o4.z = a.z + g0 * y0.z + g1 * y1.z;
    o4.w = a.w + g0 * y0.w + g1 * y1.w;
    ((float4*)(out + (ll)tk * Dm))[d4] = o4;
}

__global__ void aux_k(const int* __restrict__ cnt, const float* __restrict__ psum,
                      float* __restrict__ outp) {
    if (threadIdx.x == 0 && blockIdx.x == 0) {
        float s = 0.0f;
        for (int e = 0; e < 8; e++) s += (float)cnt[e] * psum[e];
        outp[0] = 8.0f * s * (1.0f / (2048.0f * 2048.0f));
    }
}

// ---------------- launch ----------------
extern "C" void kernel_launch(void* const* d_in, const int* in_sizes, int n_in,
                              void* d_out, int out_size, void* d_ws, size_t ws_size,
                              hipStream_t stream) {
    const float* x      = (const float*)d_in[0];
    const float* n1w    = (const float*)d_in[1];
    const float* n2w    = (const float*)d_in[2];
    const float* wq_idx = (const float*)d_in[3];
    const float* wk_idx = (const float*)d_in[4];
    const float* w_head = (const float*)d_in[5];
    const float* wq     = (const float*)d_in[6];
    const float* wk     = (const float*)d_in[7];
    const float* wvp    = (const float*)d_in[8];
    const float* wo     = (const float*)d_in[9];
    const float* rw     = (const float*)d_in[10];
    const float* rb     = (const float*)d_in[11];
    const float* w1     = (const float*)d_in[12];
    const float* b1     = (const float*)d_in[13];
    const float* w2     = (const float*)d_in[14];
    const float* b2     = (const float*)d_in[15];

    float* ws = (float*)d_ws;
    float* out  = (float*)d_out;               // [T*Dm]
    float* auxp = out + (ll)T * Dm;            // [1]
    float* idxs = auxp + 1;                    // [T*T]

    float* xn   = ws + OFF_XN;
    float* qb   = ws + OFF_Q;
    float* kb   = ws + OFF_K;
    float* vb   = ws + OFF_V;
    float* av   = ws + OFF_AV;
    float* x1   = ws + OFF_X1;
    float* x2n  = ws + OFF_X2N;
    float* qi   = ws + OFF_QI;
    float* kib  = ws + OFF_KI;
    float* hwb  = ws + OFF_HW;
    float* probs = ws + OFF_PROBS;
    float* gates = ws + OFF_GATES;
    int*   topi  = (int*)(ws + OFF_TOPI);
    int*   ptok  = (int*)(ws + OFF_PTOK);
    float* pgate = ws + OFF_PGATE;
    int*   tokp  = (int*)(ws + OFF_TOKP);
    int*   cnt   = (int*)(ws + OFF_CNT);
    float* psum  = ws + OFF_PSUM;
    int*   offs  = (int*)(ws + OFF_OFFS);
    int*   curs  = (int*)(ws + OFF_CURS);
    int*   seli  = (int*)(ws + OFF_SELI);
    int*   selc  = (int*)(ws + OFF_SELC);
    float* hmid  = ws + OFF_HMID;   // aliases xn/q (dead by MoE)
    float* yb    = ws + OFF_Y;      // aliases k/v/av (dead by MoE)

    // zero the small counter block (cnt, psum, offs, curs)
    hipMemsetAsync(ws + OFF_CNT, 0, 256, stream);

    // --- norm1 ---
    rmsnorm_k<<<T, 256, 0, stream>>>(x, n1w, xn);
    // --- indexer projections (OLD fp32 kernel: keep top-512 selection bit-stable) ---
    gemm_k<<<dim3(4, 16, 1), 256, 0, stream>>>(xn, Dm, wq_idx, 256, 0, qi, 256,
        nullptr, 0, nullptr, nullptr, nullptr, nullptr, 256, Dm, 0);
    gemm_k<<<dim3(1, 16, 1), 256, 0, stream>>>(xn, Dm, wk_idx, 64, 0, kib, 64,
        nullptr, 0, nullptr, nullptr, nullptr, nullptr, 64, Dm, 0);
    smalln_k<<<T / 4, 256, 0, stream>>>(xn, w_head, hwb, 4);
    // --- QKV: one fused multi-B launch (z selects wq/wk/wv; C offset z*T*Dm) ---
    mgemm_k<3><<<dim3(8, 16, 3), 256, 0, stream>>>(xn, Dm, wq, Dm, 0, wk, wvp, (ll)T * Dm,
        qb, Dm, nullptr, 0, nullptr, nullptr, nullptr, nullptr, Dm, Dm, 0);
    rope_k<<<4096, 256, 0, stream>>>(qb, kb);
    // --- indexer scores (full, unmasked -> output) + top-512 ---
    idx_k<<<dim3(32, 32, 1), 256, 0, stream>>>(qi, kib, hwb, idxs);
    topk_k<<<T, 256, 0, stream>>>(idxs, seli, selc);
    // --- sparse attention ---
    attn_k<<<T, 256, 0, stream>>>(qb, kb, vb, seli, selc, av);
    // --- wo + residual (6-product: feeds router selection) ---
    mgemm_k<3><<<dim3(8, 16, 1), 256, 0, stream>>>(av, Dm, wo, Dm, 0, nullptr, nullptr, 0,
        x1, Dm, nullptr, 0, x, nullptr, nullptr, nullptr, Dm, Dm, 4);
    // --- norm2 + router ---
    rmsnorm_k<<<T, 256, 0, stream>>>(x1, n2w, x2n);
    router_k<<<T / 4, 256, 0, stream>>>(x2n, rw, rb, probs, gates, topi, cnt, psum);
    offs_k<<<1, 64, 0, stream>>>(cnt, offs);
    scatter_k<<<T / 256, 256, 0, stream>>>(topi, gates, offs, curs, ptok, pgate, tokp);
    // --- MoE: 4 DFF chunks of 1024, grouped MFMA GEMMs (3-product: additive path) ---
    for (int c = 0; c < DFF / MOE_CH; c++) {
        // hmid = gelu(x2n[gather] @ w1[e][:, c*1024 .. ] + b1)
        mgemm_k<2><<<dim3(MOE_CH / 128, 16, 8), 256, 0, stream>>>(
            x2n, Dm, w1 + c * MOE_CH, DFF, (ll)Dm * DFF, nullptr, nullptr, 0,
            hmid, MOE_CH, b1 + c * MOE_CH, DFF, nullptr, ptok, cnt, offs, MOE_CH, Dm, 3);
        // y (+)= hmid @ w2[e][c*1024 .. , :]  (+ b2 on first chunk)
        mgemm_k<2><<<dim3(Dm / 128, 16, 8), 256, 0, stream>>>(
            hmid, MOE_CH, w2 + (ll)c * MOE_CH * Dm, Dm, (ll)DFF * Dm, nullptr, nullptr, 0,
            yb, Dm, b2, Dm, nullptr, nullptr, cnt, offs, Dm, MOE_CH, (c == 0) ? 1 : 8);
    }
    // --- combine + aux ---
    combine_k<<<T * Dm / 4 / 256, 256, 0, stream>>>(x1, yb, tokp, pgate, out);
    aux_k<<<1, 64, 0, stream>>>(cnt, psum, auxp);
}